// Round 2
// baseline (632.019 us; speedup 1.0000x reference)
//
#include <hip/hip_runtime.h>
#include <stdint.h>

#define H_DIM 1024
#define I_DIM 2048
#define NEXP 8
#define T_TOK 8192
#define RBLK 32   // tokens routed per block

typedef _Float16 f16;
typedef __attribute__((ext_vector_type(2))) __fp16 fp16x2;
typedef __attribute__((ext_vector_type(8))) _Float16 f16x8;
typedef __attribute__((ext_vector_type(4))) float fvec4;
typedef __attribute__((ext_vector_type(4))) float f32x4;
typedef __attribute__((ext_vector_type(4))) unsigned int uvec4;

union H8 { fp16x2 h2[4]; uvec4 v; };
union H4 { fp16x2 h2[2]; unsigned long long u; };

__device__ __forceinline__ void async_copy16(const void* g, void* l) {
    __builtin_amdgcn_global_load_lds(
        (__attribute__((address_space(1))) void*)(uintptr_t)g,
        (__attribute__((address_space(3))) void*)l,
        16, 0, 0);
}

// ---------------- convert weights fp32 -> fp16 (also zeroes expert counters) ----
__global__ void cvt_w_kernel(const float* __restrict__ wg, const float* __restrict__ wu,
                             const float* __restrict__ wd,
                             f16* __restrict__ wgh, f16* __restrict__ wuh,
                             f16* __restrict__ wdh, int* __restrict__ cnt) {
    if (blockIdx.x == 0 && blockIdx.y == 0 && threadIdx.x < NEXP)
        cnt[threadIdx.x * 32] = 0;
    const float* src; f16* dst;
    if (blockIdx.y == 0)      { src = wg; dst = wgh; }
    else if (blockIdx.y == 1) { src = wu; dst = wuh; }
    else                      { src = wd; dst = wdh; }
    size_t i = (size_t)blockIdx.x * 256 + threadIdx.x;
    const fvec4* p = (const fvec4*)src + i * 2;
    fvec4 a = p[0], b = p[1];
    H8 h;
    h.h2[0] = __builtin_amdgcn_cvt_pkrtz(a.x, a.y);
    h.h2[1] = __builtin_amdgcn_cvt_pkrtz(a.z, a.w);
    h.h2[2] = __builtin_amdgcn_cvt_pkrtz(b.x, b.y);
    h.h2[3] = __builtin_amdgcn_cvt_pkrtz(b.z, b.w);
    ((uvec4*)dst)[i] = h.v;
}

// ---------------- router: wave-per-token logits, block-aggregated slot claims ---
// Fuses x fp32->fp16 conversion. 8 global atomics per block on padded cachelines.
__global__ __launch_bounds__(256) void router_kernel(
    const float* __restrict__ x, const float* __restrict__ rw,
    int* __restrict__ cnt, int* __restrict__ tok,
    int* __restrict__ sl, float* __restrict__ sw, f16* __restrict__ xb) {
    __shared__ int   le[RBLK * 2];
    __shared__ float lw[RBLK * 2];
    __shared__ int   lpos[RBLK * 2];
    __shared__ int   lcnt[NEXP];
    __shared__ int   lbase[NEXP];
    const int w = threadIdx.x >> 6, lane = threadIdx.x & 63;
    if (threadIdx.x < NEXP) lcnt[threadIdx.x] = 0;

    for (int i = 0; i < RBLK / 4; ++i) {
        const int lt = i * 4 + w;                 // 0..RBLK-1
        const int t = blockIdx.x * RBLK + lt;
        const fvec4* xr = (const fvec4*)(x + (size_t)t * H_DIM);
        float acc[NEXP];
#pragma unroll
        for (int e = 0; e < NEXP; ++e) acc[e] = 0.f;
#pragma unroll
        for (int p = 0; p < 4; ++p) {
            int c4 = p * 64 + lane;
            fvec4 xv = xr[c4];
            H4 hh;
            hh.h2[0] = __builtin_amdgcn_cvt_pkrtz(xv.x, xv.y);
            hh.h2[1] = __builtin_amdgcn_cvt_pkrtz(xv.z, xv.w);
            ((unsigned long long*)xb)[(size_t)t * 256 + c4] = hh.u;
#pragma unroll
            for (int e = 0; e < NEXP; ++e) {
                fvec4 wv = ((const fvec4*)(rw + (size_t)e * H_DIM))[c4];
                acc[e] += xv.x * wv.x + xv.y * wv.y + xv.z * wv.z + xv.w * wv.w;
            }
        }
#pragma unroll
        for (int e = 0; e < NEXP; ++e) {
            float v = acc[e];
#pragma unroll
            for (int s = 32; s > 0; s >>= 1) v += __shfl_xor(v, s, 64);
            acc[e] = v;
        }
        if (lane == 0) {
            int i0 = 0; float m0 = acc[0];
#pragma unroll
            for (int e = 1; e < NEXP; ++e) if (acc[e] > m0) { m0 = acc[e]; i0 = e; }
            int i1 = -1; float m1 = -1e30f;
#pragma unroll
            for (int e = 0; e < NEXP; ++e) if (e != i0 && acc[e] > m1) { m1 = acc[e]; i1 = e; }
            float w0 = 1.f / (1.f + __expf(m1 - m0));
            le[lt * 2] = i0;     lw[lt * 2] = w0;
            le[lt * 2 + 1] = i1; lw[lt * 2 + 1] = 1.f - w0;
        }
    }
    __syncthreads();
    const int idx = threadIdx.x;
    if (idx < RBLK * 2) lpos[idx] = atomicAdd(&lcnt[le[idx]], 1);
    __syncthreads();
    if (idx < NEXP) lbase[idx] = atomicAdd(&cnt[idx * 32], lcnt[idx]);
    __syncthreads();
    if (idx < RBLK * 2) {
        const int e = le[idx];
        const int p = lbase[e] + lpos[idx];
        const int t = blockIdx.x * RBLK + (idx >> 1);
        tok[e * T_TOK + p] = t;
        sl[t * 2 + (idx & 1)] = (e << 20) | p;
        sw[t * 2 + (idx & 1)] = lw[idx];
    }
}

__global__ void scan_kernel(const int* __restrict__ cnt, int* __restrict__ offs) {
    if (threadIdx.x == 0) {
        int s = 0;
        for (int e = 0; e < NEXP; ++e) { offs[e] = s; s += cnt[e * 32]; }
    }
}

// LDS row = 64 halfwords = 8 chunks of 16B; chunk c of row r lives at chunk c^(r&7).
// Staging lane l writes LDS chunk (l&7) of slab-row (l>>3) -> fetch global chunk (l&7)^(l>>3).

// ---------------- GU: M=128 x N=64(per mat) tile, waves 2x2 (64x32 per wave per mat) ----
// Grid (e, rt, ct): all rt blocks of a fixed ct run consecutively on expert e's XCD,
// so the 512KB B-tile stays resident in that XCD's 4MB L2.
__global__ __launch_bounds__(256) void gu_kernel(
    const f16* __restrict__ xb, const f16* __restrict__ wgh, const f16* __restrict__ wuh,
    const int* __restrict__ cnt, const int* __restrict__ offs,
    const int* __restrict__ tok, f16* __restrict__ mid) {
    const int e = blockIdx.x, rt = blockIdx.y, ct = blockIdx.z;
    const int count = cnt[e * 32];
    if (rt * 128 >= count) return;
    const int offs_e = offs[e];

    __shared__ f16 As[128 * 64];   // 16 KB
    __shared__ f16 Bg[64 * 64];    // 8 KB
    __shared__ f16 Bu[64 * 64];    // 8 KB

    const int tid = threadIdx.x;
    const int w = tid >> 6, lane = tid & 63;
    const int wm = w & 1, wn = w >> 1;
    const int qr = lane >> 4, lc = lane & 15;
    const int rsl = lane >> 3;
    const int chk = (lane & 7) ^ rsl;

    const f16* gA[4]; f16* lA[4];
#pragma unroll
    for (int it = 0; it < 4; ++it) {
        int slab = it * 4 + w;               // 0..15
        int row = slab * 8 + rsl;            // 0..127
        int lr2 = rt * 128 + row; if (lr2 > count - 1) lr2 = count - 1;
        int t = tok[e * T_TOK + lr2];
        gA[it] = xb + (size_t)t * H_DIM + chk * 8;
        lA[it] = &As[slab * 512];
    }
    const f16* gBg[2]; const f16* gBu[2]; f16 *lBg[2], *lBu[2];
#pragma unroll
    for (int it = 0; it < 2; ++it) {
        int slab = it * 4 + w;               // 0..7
        int row = slab * 8 + rsl;            // 0..63
        int brow = ct * 64 + row;
        gBg[it] = wgh + ((size_t)e * I_DIM + brow) * H_DIM + chk * 8;
        gBu[it] = wuh + ((size_t)e * I_DIM + brow) * H_DIM + chk * 8;
        lBg[it] = &Bg[slab * 512];
        lBu[it] = &Bu[slab * 512];
    }

    // per-wave: rows wm*64..+63 (mi 0..3), cols wn*32..+31 (ni 0..1), 2 matrices
    f32x4 accg[4][2], accu[4][2];
#pragma unroll
    for (int i = 0; i < 4; ++i)
#pragma unroll
        for (int j = 0; j < 2; ++j) { accg[i][j] = (f32x4)0.f; accu[i][j] = (f32x4)0.f; }

    for (int ks = 0; ks < H_DIM / 64; ++ks) {
        const int k0 = ks * 64;
#pragma unroll
        for (int it = 0; it < 4; ++it) async_copy16(gA[it] + k0, lA[it]);
#pragma unroll
        for (int it = 0; it < 2; ++it) {
            async_copy16(gBg[it] + k0, lBg[it]);
            async_copy16(gBu[it] + k0, lBu[it]);
        }
        __syncthreads();
#pragma unroll
        for (int kk = 0; kk < 2; ++kk) {
            const int kc = kk * 4;
            const int coff = (((qr + kc) ^ (lc & 7)) << 3);
            f16x8 af[4], bg[2], bu[2];
#pragma unroll
            for (int mi = 0; mi < 4; ++mi) {
                int r = wm * 64 + mi * 16 + lc;      // 0..127
                af[mi] = *(const f16x8*)&As[r * 64 + coff];
            }
#pragma unroll
            for (int ni = 0; ni < 2; ++ni) {
                int r = wn * 32 + ni * 16 + lc;      // 0..63
                bg[ni] = *(const f16x8*)&Bg[r * 64 + coff];
                bu[ni] = *(const f16x8*)&Bu[r * 64 + coff];
            }
#pragma unroll
            for (int mi = 0; mi < 4; ++mi)
#pragma unroll
                for (int ni = 0; ni < 2; ++ni) {
                    accg[mi][ni] = __builtin_amdgcn_mfma_f32_16x16x32_f16(af[mi], bg[ni], accg[mi][ni], 0, 0, 0);
                    accu[mi][ni] = __builtin_amdgcn_mfma_f32_16x16x32_f16(af[mi], bu[ni], accu[mi][ni], 0, 0, 0);
                }
        }
        __syncthreads();
    }
#pragma unroll
    for (int mi = 0; mi < 4; ++mi)
#pragma unroll
        for (int ni = 0; ni < 2; ++ni)
#pragma unroll
            for (int r = 0; r < 4; ++r) {
                int lrow = rt * 128 + wm * 64 + mi * 16 + qr * 4 + r;
                if (lrow < count) {
                    float g = accg[mi][ni][r], u = accu[mi][ni][r];
                    float s = g / (1.f + __expf(-g)) * u;
                    mid[(size_t)(offs_e + lrow) * I_DIM + ct * 64 + wn * 32 + ni * 16 + lc] = (f16)s;
                }
            }
}

// ---------------- DOWN: M=128 x N=128 (m97 shape), fp32 stores to slot buffer ----------
// Grid (e, rt, ct) for the same L2-residency reason as gu.
__global__ __launch_bounds__(256) void down_kernel(
    const f16* __restrict__ mid, const f16* __restrict__ wdh,
    const int* __restrict__ cnt, const int* __restrict__ offs,
    float* __restrict__ mid2) {
    const int e = blockIdx.x, rt = blockIdx.y, ct = blockIdx.z;  // ct: 0..7
    const int count = cnt[e * 32];
    if (rt * 128 >= count) return;
    const int offs_e = offs[e];

    __shared__ f16 As[128 * 64];   // 16 KB
    __shared__ f16 Bd[128 * 64];   // 16 KB

    const int tid = threadIdx.x;
    const int w = tid >> 6, lane = tid & 63;
    const int wm = w & 1, wn = w >> 1;
    const int qr = lane >> 4, lc = lane & 15;
    const int rsl = lane >> 3;
    const int chk = (lane & 7) ^ rsl;

    const f16* gA[4]; f16* lA[4];
#pragma unroll
    for (int it = 0; it < 4; ++it) {
        int slab = it * 4 + w;               // 0..15
        int row = slab * 8 + rsl;
        int lr2 = rt * 128 + row; if (lr2 > count - 1) lr2 = count - 1;
        gA[it] = mid + (size_t)(offs_e + lr2) * I_DIM + chk * 8;
        lA[it] = &As[slab * 512];
    }
    const f16* gBd[4]; f16* lBd[4];
#pragma unroll
    for (int it = 0; it < 4; ++it) {
        int slab = it * 4 + w;               // 0..15
        int row = slab * 8 + rsl;            // 0..127
        int brow = ct * 128 + row;
        gBd[it] = wdh + ((size_t)e * H_DIM + brow) * I_DIM + chk * 8;
        lBd[it] = &Bd[slab * 512];
    }

    f32x4 acc[4][4];
#pragma unroll
    for (int i = 0; i < 4; ++i)
#pragma unroll
        for (int j = 0; j < 4; ++j) acc[i][j] = (f32x4)0.f;

    for (int ks = 0; ks < I_DIM / 64; ++ks) {
        const int k0 = ks * 64;
#pragma unroll
        for (int it = 0; it < 4; ++it) async_copy16(gA[it] + k0, lA[it]);
#pragma unroll
        for (int it = 0; it < 4; ++it) async_copy16(gBd[it] + k0, lBd[it]);
        __syncthreads();
#pragma unroll
        for (int kk = 0; kk < 2; ++kk) {
            const int kc = kk * 4;
            const int coff = (((qr + kc) ^ (lc & 7)) << 3);
            f16x8 af[4], bf[4];
#pragma unroll
            for (int mi = 0; mi < 4; ++mi) {
                int r = wm * 64 + mi * 16 + lc;      // 0..127
                af[mi] = *(const f16x8*)&As[r * 64 + coff];
            }
#pragma unroll
            for (int ni = 0; ni < 4; ++ni) {
                int r = wn * 64 + ni * 16 + lc;      // 0..127
                bf[ni] = *(const f16x8*)&Bd[r * 64 + coff];
            }
#pragma unroll
            for (int mi = 0; mi < 4; ++mi)
#pragma unroll
                for (int ni = 0; ni < 4; ++ni)
                    acc[mi][ni] = __builtin_amdgcn_mfma_f32_16x16x32_f16(af[mi], bf[ni], acc[mi][ni], 0, 0, 0);
        }
        __syncthreads();
    }
#pragma unroll
    for (int mi = 0; mi < 4; ++mi)
#pragma unroll
        for (int ni = 0; ni < 4; ++ni)
#pragma unroll
            for (int r = 0; r < 4; ++r) {
                int lrow = rt * 128 + wm * 64 + mi * 16 + qr * 4 + r;
                if (lrow < count) {
                    int col = ct * 128 + wn * 64 + ni * 16 + lc;
                    mid2[(size_t)(offs_e + lrow) * H_DIM + col] = acc[mi][ni][r];
                }
            }
}

// ---------------- combine: out[t] = w0*mid2[slot0] + w1*mid2[slot1] ----------------
__global__ void combine_kernel(const float* __restrict__ mid2, const int* __restrict__ sl,
                               const float* __restrict__ sw, const int* __restrict__ offs,
                               fvec4* __restrict__ out) {
    const int t = blockIdx.x;
    const int c = threadIdx.x;               // 0..255 float4 per 1024-col row
    int s0 = sl[t * 2], s1 = sl[t * 2 + 1];
    float w0 = sw[t * 2], w1 = sw[t * 2 + 1];
    size_t r0 = (size_t)(offs[s0 >> 20] + (s0 & 0xFFFFF)) * 256 + c;
    size_t r1 = (size_t)(offs[s1 >> 20] + (s1 & 0xFFFFF)) * 256 + c;
    const fvec4* m4 = (const fvec4*)mid2;
    fvec4 a = m4[r0], b = m4[r1];
    out[(size_t)t * 256 + c] = w0 * a + w1 * b;
}

extern "C" void kernel_launch(void* const* d_in, const int* in_sizes, int n_in,
                              void* d_out, int out_size, void* d_ws, size_t ws_size,
                              hipStream_t stream) {
    (void)in_sizes; (void)n_in; (void)out_size; (void)ws_size;
    const float* x  = (const float*)d_in[0];
    const float* rw = (const float*)d_in[1];
    const float* wg = (const float*)d_in[2];
    const float* wu = (const float*)d_in[3];
    const float* wd = (const float*)d_in[4];
    float* out = (float*)d_out;

    uint8_t* ws = (uint8_t*)d_ws;
    int*   cnt  = (int*)(ws + 0);              // 8 counters, 128B apart (1024 B)
    int*   offs = (int*)(ws + 1024);
    int*   tok  = (int*)(ws + 4096);           // 8*8192 ints = 262144 B
    int*   sl   = (int*)(ws + 266240);         // 2*8192 ints = 65536 B
    float* sw   = (float*)(ws + 331776);       // 2*8192 floats = 65536 B
    f16*   xb   = (f16*)(ws + 528384);         // 16,777,216 B
    f16*   mid  = (f16*)(ws + 17305600);       // 16384*2048 f16 = 67,108,864 B
    f16*   wgh  = (f16*)(ws + 84414464);       // 33,554,432 B
    f16*   wuh  = (f16*)(ws + 117968896);      // 33,554,432 B
    f16*   wdh  = (f16*)(ws + 151523328);      // 33,554,432 B  (end 185,077,760)
    // mid2 fp32 [16384][1024] overlays wgh+wuh (dead after gu; rewritten by cvt_w each call)
    float* mid2 = (float*)(ws + 84414464);     // 67,108,864 B

    hipLaunchKernelGGL(cvt_w_kernel, dim3(8192, 3), dim3(256), 0, stream, wg, wu, wd, wgh, wuh, wdh, cnt);
    hipLaunchKernelGGL(router_kernel, dim3(T_TOK / RBLK), dim3(256), 0, stream, x, rw, cnt, tok, sl, sw, xb);
    hipLaunchKernelGGL(scan_kernel, dim3(1), dim3(64), 0, stream, cnt, offs);
    // grid: (expert, rt, ct) -> expert pins to an XCD; rt-major order keeps the
    // current B-tile (512 KB) resident in that XCD's L2 across the whole rt sweep
    hipLaunchKernelGGL(gu_kernel, dim3(8, 64, 32), dim3(256), 0, stream, xb, wgh, wuh, cnt, offs, tok, mid);
    hipLaunchKernelGGL(down_kernel, dim3(8, 64, 8), dim3(256), 0, stream, mid, wdh, cnt, offs, mid2);
    hipLaunchKernelGGL(combine_kernel, dim3(8192), dim3(256), 0, stream, mid2, sl, sw, offs, (fvec4*)out);
}

// Round 3
// 571.970 us; speedup vs baseline: 1.1050x; 1.1050x over previous
//
#include <hip/hip_runtime.h>
#include <stdint.h>

#define H_DIM 1024
#define I_DIM 2048
#define NEXP 8
#define T_TOK 8192
#define RBLK 32   // tokens routed per block

typedef _Float16 f16;
typedef __attribute__((ext_vector_type(2))) __fp16 fp16x2;
typedef __attribute__((ext_vector_type(8))) _Float16 f16x8;
typedef __attribute__((ext_vector_type(4))) float fvec4;
typedef __attribute__((ext_vector_type(4))) float f32x4;
typedef __attribute__((ext_vector_type(4))) unsigned int uvec4;

union H8 { fp16x2 h2[4]; uvec4 v; };
union H4 { fp16x2 h2[2]; unsigned long long u; };

__device__ __forceinline__ void async_copy16(const void* g, void* l) {
    __builtin_amdgcn_global_load_lds(
        (__attribute__((address_space(1))) void*)(uintptr_t)g,
        (__attribute__((address_space(3))) void*)l,
        16, 0, 0);
}

// ---------------- convert weights fp32 -> fp16 (also zeroes expert counters) ----
__global__ void cvt_w_kernel(const float* __restrict__ wg, const float* __restrict__ wu,
                             const float* __restrict__ wd,
                             f16* __restrict__ wgh, f16* __restrict__ wuh,
                             f16* __restrict__ wdh, int* __restrict__ cnt) {
    if (blockIdx.x == 0 && blockIdx.y == 0 && threadIdx.x < NEXP)
        cnt[threadIdx.x * 32] = 0;
    const float* src; f16* dst;
    if (blockIdx.y == 0)      { src = wg; dst = wgh; }
    else if (blockIdx.y == 1) { src = wu; dst = wuh; }
    else                      { src = wd; dst = wdh; }
    size_t i = (size_t)blockIdx.x * 256 + threadIdx.x;
    const fvec4* p = (const fvec4*)src + i * 2;
    fvec4 a = p[0], b = p[1];
    H8 h;
    h.h2[0] = __builtin_amdgcn_cvt_pkrtz(a.x, a.y);
    h.h2[1] = __builtin_amdgcn_cvt_pkrtz(a.z, a.w);
    h.h2[2] = __builtin_amdgcn_cvt_pkrtz(b.x, b.y);
    h.h2[3] = __builtin_amdgcn_cvt_pkrtz(b.z, b.w);
    ((uvec4*)dst)[i] = h.v;
}

// ---------------- router: wave-per-token logits, block-aggregated slot claims ---
// Fuses x fp32->fp16 conversion. 8 global atomics per block on padded cachelines.
__global__ __launch_bounds__(256) void router_kernel(
    const float* __restrict__ x, const float* __restrict__ rw,
    int* __restrict__ cnt, int* __restrict__ tok,
    int* __restrict__ sl, float* __restrict__ sw, f16* __restrict__ xb) {
    __shared__ int   le[RBLK * 2];
    __shared__ float lw[RBLK * 2];
    __shared__ int   lpos[RBLK * 2];
    __shared__ int   lcnt[NEXP];
    __shared__ int   lbase[NEXP];
    const int w = threadIdx.x >> 6, lane = threadIdx.x & 63;
    if (threadIdx.x < NEXP) lcnt[threadIdx.x] = 0;

    for (int i = 0; i < RBLK / 4; ++i) {
        const int lt = i * 4 + w;                 // 0..RBLK-1
        const int t = blockIdx.x * RBLK + lt;
        const fvec4* xr = (const fvec4*)(x + (size_t)t * H_DIM);
        float acc[NEXP];
#pragma unroll
        for (int e = 0; e < NEXP; ++e) acc[e] = 0.f;
#pragma unroll
        for (int p = 0; p < 4; ++p) {
            int c4 = p * 64 + lane;
            fvec4 xv = xr[c4];
            H4 hh;
            hh.h2[0] = __builtin_amdgcn_cvt_pkrtz(xv.x, xv.y);
            hh.h2[1] = __builtin_amdgcn_cvt_pkrtz(xv.z, xv.w);
            ((unsigned long long*)xb)[(size_t)t * 256 + c4] = hh.u;
#pragma unroll
            for (int e = 0; e < NEXP; ++e) {
                fvec4 wv = ((const fvec4*)(rw + (size_t)e * H_DIM))[c4];
                acc[e] += xv.x * wv.x + xv.y * wv.y + xv.z * wv.z + xv.w * wv.w;
            }
        }
#pragma unroll
        for (int e = 0; e < NEXP; ++e) {
            float v = acc[e];
#pragma unroll
            for (int s = 32; s > 0; s >>= 1) v += __shfl_xor(v, s, 64);
            acc[e] = v;
        }
        if (lane == 0) {
            int i0 = 0; float m0 = acc[0];
#pragma unroll
            for (int e = 1; e < NEXP; ++e) if (acc[e] > m0) { m0 = acc[e]; i0 = e; }
            int i1 = -1; float m1 = -1e30f;
#pragma unroll
            for (int e = 0; e < NEXP; ++e) if (e != i0 && acc[e] > m1) { m1 = acc[e]; i1 = e; }
            float w0 = 1.f / (1.f + __expf(m1 - m0));
            le[lt * 2] = i0;     lw[lt * 2] = w0;
            le[lt * 2 + 1] = i1; lw[lt * 2 + 1] = 1.f - w0;
        }
    }
    __syncthreads();
    const int idx = threadIdx.x;
    if (idx < RBLK * 2) lpos[idx] = atomicAdd(&lcnt[le[idx]], 1);
    __syncthreads();
    if (idx < NEXP) lbase[idx] = atomicAdd(&cnt[idx * 32], lcnt[idx]);
    __syncthreads();
    if (idx < RBLK * 2) {
        const int e = le[idx];
        const int p = lbase[e] + lpos[idx];
        const int t = blockIdx.x * RBLK + (idx >> 1);
        tok[e * T_TOK + p] = t;
        sl[t * 2 + (idx & 1)] = (e << 20) | p;
        sw[t * 2 + (idx & 1)] = lw[idx];
    }
}

__global__ void scan_kernel(const int* __restrict__ cnt, int* __restrict__ offs) {
    if (threadIdx.x == 0) {
        int s = 0;
        for (int e = 0; e < NEXP; ++e) { offs[e] = s; s += cnt[e * 32]; }
    }
}

// LDS row = 64 halfwords = 8 chunks of 16B; chunk c of row r lives at chunk c^(r&7).
// Staging lane l writes LDS chunk (l&7) of slab-row (l>>3) -> fetch global chunk (l&7)^(l>>3).

// ---------------- GU: M=128 x N=64(per mat) tile, waves 2x2 (64x32 per wave per mat) ----
// Grid (e, ct, rt) with ct FAST: all working blocks (rt < ntiles) are dense at the
// front of dispatch order; empty rt blocks trail. (Round-2's rt-fast order caused
// bursty dispatch starvation: occupancy 28->18.8%, dur +45%.)
__global__ __launch_bounds__(256) void gu_kernel(
    const f16* __restrict__ xb, const f16* __restrict__ wgh, const f16* __restrict__ wuh,
    const int* __restrict__ cnt, const int* __restrict__ offs,
    const int* __restrict__ tok, f16* __restrict__ mid) {
    const int e = blockIdx.x, ct = blockIdx.y, rt = blockIdx.z;
    const int count = cnt[e * 32];
    if (rt * 128 >= count) return;
    const int offs_e = offs[e];

    __shared__ f16 As[128 * 64];   // 16 KB
    __shared__ f16 Bg[64 * 64];    // 8 KB
    __shared__ f16 Bu[64 * 64];    // 8 KB

    const int tid = threadIdx.x;
    const int w = tid >> 6, lane = tid & 63;
    const int wm = w & 1, wn = w >> 1;
    const int qr = lane >> 4, lc = lane & 15;
    const int rsl = lane >> 3;
    const int chk = (lane & 7) ^ rsl;

    const f16* gA[4]; f16* lA[4];
#pragma unroll
    for (int it = 0; it < 4; ++it) {
        int slab = it * 4 + w;               // 0..15
        int row = slab * 8 + rsl;            // 0..127
        int lr2 = rt * 128 + row; if (lr2 > count - 1) lr2 = count - 1;
        int t = tok[e * T_TOK + lr2];
        gA[it] = xb + (size_t)t * H_DIM + chk * 8;
        lA[it] = &As[slab * 512];
    }
    const f16* gBg[2]; const f16* gBu[2]; f16 *lBg[2], *lBu[2];
#pragma unroll
    for (int it = 0; it < 2; ++it) {
        int slab = it * 4 + w;               // 0..7
        int row = slab * 8 + rsl;            // 0..63
        int brow = ct * 64 + row;
        gBg[it] = wgh + ((size_t)e * I_DIM + brow) * H_DIM + chk * 8;
        gBu[it] = wuh + ((size_t)e * I_DIM + brow) * H_DIM + chk * 8;
        lBg[it] = &Bg[slab * 512];
        lBu[it] = &Bu[slab * 512];
    }

    // per-wave: rows wm*64..+63 (mi 0..3), cols wn*32..+31 (ni 0..1), 2 matrices
    f32x4 accg[4][2], accu[4][2];
#pragma unroll
    for (int i = 0; i < 4; ++i)
#pragma unroll
        for (int j = 0; j < 2; ++j) { accg[i][j] = (f32x4)0.f; accu[i][j] = (f32x4)0.f; }

    for (int ks = 0; ks < H_DIM / 64; ++ks) {
        const int k0 = ks * 64;
#pragma unroll
        for (int it = 0; it < 4; ++it) async_copy16(gA[it] + k0, lA[it]);
#pragma unroll
        for (int it = 0; it < 2; ++it) {
            async_copy16(gBg[it] + k0, lBg[it]);
            async_copy16(gBu[it] + k0, lBu[it]);
        }
        __syncthreads();
#pragma unroll
        for (int kk = 0; kk < 2; ++kk) {
            const int kc = kk * 4;
            const int coff = (((qr + kc) ^ (lc & 7)) << 3);
            f16x8 af[4], bg[2], bu[2];
#pragma unroll
            for (int mi = 0; mi < 4; ++mi) {
                int r = wm * 64 + mi * 16 + lc;      // 0..127
                af[mi] = *(const f16x8*)&As[r * 64 + coff];
            }
#pragma unroll
            for (int ni = 0; ni < 2; ++ni) {
                int r = wn * 32 + ni * 16 + lc;      // 0..63
                bg[ni] = *(const f16x8*)&Bg[r * 64 + coff];
                bu[ni] = *(const f16x8*)&Bu[r * 64 + coff];
            }
#pragma unroll
            for (int mi = 0; mi < 4; ++mi)
#pragma unroll
                for (int ni = 0; ni < 2; ++ni) {
                    accg[mi][ni] = __builtin_amdgcn_mfma_f32_16x16x32_f16(af[mi], bg[ni], accg[mi][ni], 0, 0, 0);
                    accu[mi][ni] = __builtin_amdgcn_mfma_f32_16x16x32_f16(af[mi], bu[ni], accu[mi][ni], 0, 0, 0);
                }
        }
        __syncthreads();
    }
#pragma unroll
    for (int mi = 0; mi < 4; ++mi)
#pragma unroll
        for (int ni = 0; ni < 2; ++ni)
#pragma unroll
            for (int r = 0; r < 4; ++r) {
                int lrow = rt * 128 + wm * 64 + mi * 16 + qr * 4 + r;
                if (lrow < count) {
                    float g = accg[mi][ni][r], u = accu[mi][ni][r];
                    float s = g / (1.f + __expf(-g)) * u;
                    mid[(size_t)(offs_e + lrow) * I_DIM + ct * 64 + wn * 32 + ni * 16 + lc] = (f16)s;
                }
            }
}

// ---------------- DOWN: M=128 x N=128 (m97 shape), fp32 stores to slot buffer ----------
// Grid (e, ct, rt) with ct fast, rt slow (dense-work-first dispatch order).
__global__ __launch_bounds__(256) void down_kernel(
    const f16* __restrict__ mid, const f16* __restrict__ wdh,
    const int* __restrict__ cnt, const int* __restrict__ offs,
    float* __restrict__ mid2) {
    const int e = blockIdx.x, ct = blockIdx.y, rt = blockIdx.z;  // ct: 0..7
    const int count = cnt[e * 32];
    if (rt * 128 >= count) return;
    const int offs_e = offs[e];

    __shared__ f16 As[128 * 64];   // 16 KB
    __shared__ f16 Bd[128 * 64];   // 16 KB

    const int tid = threadIdx.x;
    const int w = tid >> 6, lane = tid & 63;
    const int wm = w & 1, wn = w >> 1;
    const int qr = lane >> 4, lc = lane & 15;
    const int rsl = lane >> 3;
    const int chk = (lane & 7) ^ rsl;

    const f16* gA[4]; f16* lA[4];
#pragma unroll
    for (int it = 0; it < 4; ++it) {
        int slab = it * 4 + w;               // 0..15
        int row = slab * 8 + rsl;
        int lr2 = rt * 128 + row; if (lr2 > count - 1) lr2 = count - 1;
        gA[it] = mid + (size_t)(offs_e + lr2) * I_DIM + chk * 8;
        lA[it] = &As[slab * 512];
    }
    const f16* gBd[4]; f16* lBd[4];
#pragma unroll
    for (int it = 0; it < 4; ++it) {
        int slab = it * 4 + w;               // 0..15
        int row = slab * 8 + rsl;            // 0..127
        int brow = ct * 128 + row;
        gBd[it] = wdh + ((size_t)e * H_DIM + brow) * I_DIM + chk * 8;
        lBd[it] = &Bd[slab * 512];
    }

    f32x4 acc[4][4];
#pragma unroll
    for (int i = 0; i < 4; ++i)
#pragma unroll
        for (int j = 0; j < 4; ++j) acc[i][j] = (f32x4)0.f;

    for (int ks = 0; ks < I_DIM / 64; ++ks) {
        const int k0 = ks * 64;
#pragma unroll
        for (int it = 0; it < 4; ++it) async_copy16(gA[it] + k0, lA[it]);
#pragma unroll
        for (int it = 0; it < 4; ++it) async_copy16(gBd[it] + k0, lBd[it]);
        __syncthreads();
#pragma unroll
        for (int kk = 0; kk < 2; ++kk) {
            const int kc = kk * 4;
            const int coff = (((qr + kc) ^ (lc & 7)) << 3);
            f16x8 af[4], bf[4];
#pragma unroll
            for (int mi = 0; mi < 4; ++mi) {
                int r = wm * 64 + mi * 16 + lc;      // 0..127
                af[mi] = *(const f16x8*)&As[r * 64 + coff];
            }
#pragma unroll
            for (int ni = 0; ni < 4; ++ni) {
                int r = wn * 64 + ni * 16 + lc;      // 0..127
                bf[ni] = *(const f16x8*)&Bd[r * 64 + coff];
            }
#pragma unroll
            for (int mi = 0; mi < 4; ++mi)
#pragma unroll
                for (int ni = 0; ni < 4; ++ni)
                    acc[mi][ni] = __builtin_amdgcn_mfma_f32_16x16x32_f16(af[mi], bf[ni], acc[mi][ni], 0, 0, 0);
        }
        __syncthreads();
    }
#pragma unroll
    for (int mi = 0; mi < 4; ++mi)
#pragma unroll
        for (int ni = 0; ni < 4; ++ni)
#pragma unroll
            for (int r = 0; r < 4; ++r) {
                int lrow = rt * 128 + wm * 64 + mi * 16 + qr * 4 + r;
                if (lrow < count) {
                    int col = ct * 128 + wn * 64 + ni * 16 + lc;
                    mid2[(size_t)(offs_e + lrow) * H_DIM + col] = acc[mi][ni][r];
                }
            }
}

// ---------------- combine: out[t] = w0*mid2[slot0] + w1*mid2[slot1] ----------------
__global__ void combine_kernel(const float* __restrict__ mid2, const int* __restrict__ sl,
                               const float* __restrict__ sw, const int* __restrict__ offs,
                               fvec4* __restrict__ out) {
    const int t = blockIdx.x;
    const int c = threadIdx.x;               // 0..255 float4 per 1024-col row
    int s0 = sl[t * 2], s1 = sl[t * 2 + 1];
    float w0 = sw[t * 2], w1 = sw[t * 2 + 1];
    size_t r0 = (size_t)(offs[s0 >> 20] + (s0 & 0xFFFFF)) * 256 + c;
    size_t r1 = (size_t)(offs[s1 >> 20] + (s1 & 0xFFFFF)) * 256 + c;
    const fvec4* m4 = (const fvec4*)mid2;
    fvec4 a = m4[r0], b = m4[r1];
    out[(size_t)t * 256 + c] = w0 * a + w1 * b;
}

extern "C" void kernel_launch(void* const* d_in, const int* in_sizes, int n_in,
                              void* d_out, int out_size, void* d_ws, size_t ws_size,
                              hipStream_t stream) {
    (void)in_sizes; (void)n_in; (void)out_size; (void)ws_size;
    const float* x  = (const float*)d_in[0];
    const float* rw = (const float*)d_in[1];
    const float* wg = (const float*)d_in[2];
    const float* wu = (const float*)d_in[3];
    const float* wd = (const float*)d_in[4];
    float* out = (float*)d_out;

    uint8_t* ws = (uint8_t*)d_ws;
    int*   cnt  = (int*)(ws + 0);              // 8 counters, 128B apart (1024 B)
    int*   offs = (int*)(ws + 1024);
    int*   tok  = (int*)(ws + 4096);           // 8*8192 ints = 262144 B
    int*   sl   = (int*)(ws + 266240);         // 2*8192 ints = 65536 B
    float* sw   = (float*)(ws + 331776);       // 2*8192 floats = 65536 B
    f16*   xb   = (f16*)(ws + 528384);         // 16,777,216 B
    f16*   mid  = (f16*)(ws + 17305600);       // 16384*2048 f16 = 67,108,864 B
    f16*   wgh  = (f16*)(ws + 84414464);       // 33,554,432 B
    f16*   wuh  = (f16*)(ws + 117968896);      // 33,554,432 B
    f16*   wdh  = (f16*)(ws + 151523328);      // 33,554,432 B  (end 185,077,760)
    // mid2 fp32 [16384][1024] overlays wgh+wuh (dead after gu; rewritten by cvt_w each call)
    float* mid2 = (float*)(ws + 84414464);     // 67,108,864 B

    hipLaunchKernelGGL(cvt_w_kernel, dim3(8192, 3), dim3(256), 0, stream, wg, wu, wd, wgh, wuh, wdh, cnt);
    hipLaunchKernelGGL(router_kernel, dim3(T_TOK / RBLK), dim3(256), 0, stream, x, rw, cnt, tok, sl, sw, xb);
    hipLaunchKernelGGL(scan_kernel, dim3(1), dim3(64), 0, stream, cnt, offs);
    // grid: (expert, ct, rt) -> expert pins to an XCD; ct-fast keeps all working
    // blocks dense at the head of dispatch order (empty rt-tail blocks last)
    hipLaunchKernelGGL(gu_kernel, dim3(8, 32, 64), dim3(256), 0, stream, xb, wgh, wuh, cnt, offs, tok, mid);
    hipLaunchKernelGGL(down_kernel, dim3(8, 8, 64), dim3(256), 0, stream, mid, wdh, cnt, offs, mid2);
    hipLaunchKernelGGL(combine_kernel, dim3(8192), dim3(256), 0, stream, mid2, sl, sw, offs, (fvec4*)out);
}

// Round 4
// 535.052 us; speedup vs baseline: 1.1812x; 1.0690x over previous
//
#include <hip/hip_runtime.h>
#include <stdint.h>

#define H_DIM 1024
#define I_DIM 2048
#define NEXP 8
#define T_TOK 8192
#define RBLK 32   // tokens routed per block
#define CVT_BLOCKS 24576   // 3 * 8192 weight-convert blocks in prep_kernel

typedef _Float16 f16;
typedef __attribute__((ext_vector_type(2))) __fp16 fp16x2;
typedef __attribute__((ext_vector_type(8))) _Float16 f16x8;
typedef __attribute__((ext_vector_type(4))) float fvec4;
typedef __attribute__((ext_vector_type(4))) float f32x4;
typedef __attribute__((ext_vector_type(4))) unsigned int uvec4;

union H8 { fp16x2 h2[4]; uvec4 v; };
union H4 { fp16x2 h2[2]; unsigned long long u; };

__device__ __forceinline__ void async_copy16(const void* g, void* l) {
    __builtin_amdgcn_global_load_lds(
        (__attribute__((address_space(1))) void*)(uintptr_t)g,
        (__attribute__((address_space(3))) void*)l,
        16, 0, 0);
}

// ---------------- init: zero expert counts (padded: 1 counter per 128B line) ----
// Must be its own launch: every router atomic in prep_kernel must observe 0.
__global__ void init_kernel(int* __restrict__ cnt) {
    if (threadIdx.x < NEXP) cnt[threadIdx.x * 32] = 0;
}

// ---------------- prep: weight cvt (blocks 0..24575) + router (blocks 24576..24831) ----
// Fusing lets the router's low-BW, VALU-light work (was 15us serialized) hide
// under the BW-bound weight conversion stream.
__global__ __launch_bounds__(256) void prep_kernel(
    const float* __restrict__ wg, const float* __restrict__ wu, const float* __restrict__ wd,
    f16* __restrict__ wgh, f16* __restrict__ wuh, f16* __restrict__ wdh,
    const float* __restrict__ x, const float* __restrict__ rw,
    int* __restrict__ cnt, int* __restrict__ tok,
    int* __restrict__ sl, float* __restrict__ sw, f16* __restrict__ xb) {
    __shared__ int   le[RBLK * 2];
    __shared__ float lw[RBLK * 2];
    __shared__ int   lpos[RBLK * 2];
    __shared__ int   lcnt[NEXP];
    __shared__ int   lbase[NEXP];

    const int b = blockIdx.x;
    if (b < CVT_BLOCKS) {
        // ---- weight fp32 -> fp16 conversion ----
        const int role = b >> 13;              // /8192
        const float* src; f16* dst;
        if (role == 0)      { src = wg; dst = wgh; }
        else if (role == 1) { src = wu; dst = wuh; }
        else                { src = wd; dst = wdh; }
        size_t i = (size_t)(b & 8191) * 256 + threadIdx.x;
        const fvec4* p = (const fvec4*)src + i * 2;
        fvec4 a = p[0], bb = p[1];
        H8 h;
        h.h2[0] = __builtin_amdgcn_cvt_pkrtz(a.x, a.y);
        h.h2[1] = __builtin_amdgcn_cvt_pkrtz(a.z, a.w);
        h.h2[2] = __builtin_amdgcn_cvt_pkrtz(bb.x, bb.y);
        h.h2[3] = __builtin_amdgcn_cvt_pkrtz(bb.z, bb.w);
        ((uvec4*)dst)[i] = h.v;
        return;
    }

    // ---- router: wave-per-token logits, block-aggregated slot claims ----
    // Fuses x fp32->fp16. 8 global atomics per block on padded cachelines.
    const int rb = b - CVT_BLOCKS;             // 0..255
    const int w = threadIdx.x >> 6, lane = threadIdx.x & 63;
    if (threadIdx.x < NEXP) lcnt[threadIdx.x] = 0;

    for (int i = 0; i < RBLK / 4; ++i) {
        const int lt = i * 4 + w;              // 0..RBLK-1
        const int t = rb * RBLK + lt;
        const fvec4* xr = (const fvec4*)(x + (size_t)t * H_DIM);
        float acc[NEXP];
#pragma unroll
        for (int e = 0; e < NEXP; ++e) acc[e] = 0.f;
#pragma unroll
        for (int p = 0; p < 4; ++p) {
            int c4 = p * 64 + lane;
            fvec4 xv = xr[c4];
            H4 hh;
            hh.h2[0] = __builtin_amdgcn_cvt_pkrtz(xv.x, xv.y);
            hh.h2[1] = __builtin_amdgcn_cvt_pkrtz(xv.z, xv.w);
            ((unsigned long long*)xb)[(size_t)t * 256 + c4] = hh.u;
#pragma unroll
            for (int e = 0; e < NEXP; ++e) {
                fvec4 wv = ((const fvec4*)(rw + (size_t)e * H_DIM))[c4];
                acc[e] += xv.x * wv.x + xv.y * wv.y + xv.z * wv.z + xv.w * wv.w;
            }
        }
#pragma unroll
        for (int e = 0; e < NEXP; ++e) {
            float v = acc[e];
#pragma unroll
            for (int s = 32; s > 0; s >>= 1) v += __shfl_xor(v, s, 64);
            acc[e] = v;
        }
        if (lane == 0) {
            int i0 = 0; float m0 = acc[0];
#pragma unroll
            for (int e = 1; e < NEXP; ++e) if (acc[e] > m0) { m0 = acc[e]; i0 = e; }
            int i1 = -1; float m1 = -1e30f;
#pragma unroll
            for (int e = 0; e < NEXP; ++e) if (e != i0 && acc[e] > m1) { m1 = acc[e]; i1 = e; }
            float w0 = 1.f / (1.f + __expf(m1 - m0));
            le[lt * 2] = i0;     lw[lt * 2] = w0;
            le[lt * 2 + 1] = i1; lw[lt * 2 + 1] = 1.f - w0;
        }
    }
    __syncthreads();
    const int idx = threadIdx.x;
    if (idx < RBLK * 2) lpos[idx] = atomicAdd(&lcnt[le[idx]], 1);
    __syncthreads();
    if (idx < NEXP) lbase[idx] = atomicAdd(&cnt[idx * 32], lcnt[idx]);
    __syncthreads();
    if (idx < RBLK * 2) {
        const int e = le[idx];
        const int p = lbase[e] + lpos[idx];
        const int t = rb * RBLK + (idx >> 1);
        tok[e * T_TOK + p] = t;
        sl[t * 2 + (idx & 1)] = (e << 20) | p;
        sw[t * 2 + (idx & 1)] = lw[idx];
    }
}

// LDS row = 64 halfwords = 8 chunks of 16B; chunk c of row r lives at chunk c^(r&7).
// Staging lane l writes LDS chunk (l&7) of slab-row (l>>3) -> fetch global chunk (l&7)^(l>>3).

// ---------------- GU: M=128 x N=64(per mat), w-strip waves (round-1 proven shape) ----
// Each wave owns rows w*32..w*32+31 (mi 0..1) and ALL 64 N cols (ni 0..3) of both
// mats. (Round-3 A/B: 2x2 wave split regressed 180->220us despite fewer ds_reads.)
// Grid (e, ct, rt): ct fast keeps working blocks dense in dispatch order.
__global__ __launch_bounds__(256) void gu_kernel(
    const f16* __restrict__ xb, const f16* __restrict__ wgh, const f16* __restrict__ wuh,
    const int* __restrict__ cnt,
    const int* __restrict__ tok, f16* __restrict__ mid) {
    const int e = blockIdx.x, ct = blockIdx.y, rt = blockIdx.z;
    const int count = cnt[e * 32];
    if (rt * 128 >= count) return;
    int offs_e = 0;                            // inline prefix (scan kernel removed)
#pragma unroll
    for (int i2 = 0; i2 < NEXP; ++i2) offs_e += (i2 < e) ? cnt[i2 * 32] : 0;

    __shared__ f16 As[128 * 64];   // 16 KB
    __shared__ f16 Bg[64 * 64];    // 8 KB
    __shared__ f16 Bu[64 * 64];    // 8 KB

    const int tid = threadIdx.x;
    const int w = tid >> 6, lane = tid & 63;
    const int qr = lane >> 4, lc = lane & 15;
    const int rsl = lane >> 3;
    const int chk = (lane & 7) ^ rsl;

    const f16* gA[4]; f16* lA[4];
#pragma unroll
    for (int it = 0; it < 4; ++it) {
        int slab = it * 4 + w;               // 0..15
        int row = slab * 8 + rsl;            // 0..127
        int lr2 = rt * 128 + row; if (lr2 > count - 1) lr2 = count - 1;
        int t = tok[e * T_TOK + lr2];
        gA[it] = xb + (size_t)t * H_DIM + chk * 8;
        lA[it] = &As[slab * 512];
    }
    const f16* gBg[2]; const f16* gBu[2]; f16 *lBg[2], *lBu[2];
#pragma unroll
    for (int it = 0; it < 2; ++it) {
        int slab = it * 4 + w;               // 0..7
        int row = slab * 8 + rsl;            // 0..63
        int brow = ct * 64 + row;
        gBg[it] = wgh + ((size_t)e * I_DIM + brow) * H_DIM + chk * 8;
        gBu[it] = wuh + ((size_t)e * I_DIM + brow) * H_DIM + chk * 8;
        lBg[it] = &Bg[slab * 512];
        lBu[it] = &Bu[slab * 512];
    }

    // per-wave: M-strip w*32..w*32+31 (mi 0..1), all 64 N cols (ni 0..3), 2 matrices
    f32x4 accg[2][4], accu[2][4];
#pragma unroll
    for (int i = 0; i < 2; ++i)
#pragma unroll
        for (int j = 0; j < 4; ++j) { accg[i][j] = (f32x4)0.f; accu[i][j] = (f32x4)0.f; }

    for (int ks = 0; ks < H_DIM / 64; ++ks) {
        const int k0 = ks * 64;
#pragma unroll
        for (int it = 0; it < 4; ++it) async_copy16(gA[it] + k0, lA[it]);
#pragma unroll
        for (int it = 0; it < 2; ++it) {
            async_copy16(gBg[it] + k0, lBg[it]);
            async_copy16(gBu[it] + k0, lBu[it]);
        }
        __syncthreads();
#pragma unroll
        for (int kk = 0; kk < 2; ++kk) {
            const int kc = kk * 4;
            const int coff = (((qr + kc) ^ (lc & 7)) << 3);
            f16x8 af[2], bg[4], bu[4];
#pragma unroll
            for (int mi = 0; mi < 2; ++mi) {
                int r = w * 32 + mi * 16 + lc;       // 0..127
                af[mi] = *(const f16x8*)&As[r * 64 + coff];
            }
#pragma unroll
            for (int ni = 0; ni < 4; ++ni) {
                int r = ni * 16 + lc;                // 0..63
                bg[ni] = *(const f16x8*)&Bg[r * 64 + coff];
                bu[ni] = *(const f16x8*)&Bu[r * 64 + coff];
            }
#pragma unroll
            for (int mi = 0; mi < 2; ++mi)
#pragma unroll
                for (int ni = 0; ni < 4; ++ni) {
                    accg[mi][ni] = __builtin_amdgcn_mfma_f32_16x16x32_f16(af[mi], bg[ni], accg[mi][ni], 0, 0, 0);
                    accu[mi][ni] = __builtin_amdgcn_mfma_f32_16x16x32_f16(af[mi], bu[ni], accu[mi][ni], 0, 0, 0);
                }
        }
        __syncthreads();
    }
#pragma unroll
    for (int mi = 0; mi < 2; ++mi)
#pragma unroll
        for (int ni = 0; ni < 4; ++ni)
#pragma unroll
            for (int r = 0; r < 4; ++r) {
                int lrow = rt * 128 + w * 32 + mi * 16 + qr * 4 + r;
                if (lrow < count) {
                    float g = accg[mi][ni][r], u = accu[mi][ni][r];
                    float s = g / (1.f + __expf(-g)) * u;
                    mid[(size_t)(offs_e + lrow) * I_DIM + ct * 64 + ni * 16 + lc] = (f16)s;
                }
            }
}

// ---------------- DOWN: M=128 x N=128 (m97 shape), fp32 stores to slot buffer ----------
// Grid (e, ct, rt) with ct fast, rt slow (dense-work-first dispatch order).
__global__ __launch_bounds__(256) void down_kernel(
    const f16* __restrict__ mid, const f16* __restrict__ wdh,
    const int* __restrict__ cnt,
    float* __restrict__ mid2) {
    const int e = blockIdx.x, ct = blockIdx.y, rt = blockIdx.z;  // ct: 0..7
    const int count = cnt[e * 32];
    if (rt * 128 >= count) return;
    int offs_e = 0;                            // inline prefix (scan kernel removed)
#pragma unroll
    for (int i2 = 0; i2 < NEXP; ++i2) offs_e += (i2 < e) ? cnt[i2 * 32] : 0;

    __shared__ f16 As[128 * 64];   // 16 KB
    __shared__ f16 Bd[128 * 64];   // 16 KB

    const int tid = threadIdx.x;
    const int w = tid >> 6, lane = tid & 63;
    const int wm = w & 1, wn = w >> 1;
    const int qr = lane >> 4, lc = lane & 15;
    const int rsl = lane >> 3;
    const int chk = (lane & 7) ^ rsl;

    const f16* gA[4]; f16* lA[4];
#pragma unroll
    for (int it = 0; it < 4; ++it) {
        int slab = it * 4 + w;               // 0..15
        int row = slab * 8 + rsl;
        int lr2 = rt * 128 + row; if (lr2 > count - 1) lr2 = count - 1;
        gA[it] = mid + (size_t)(offs_e + lr2) * I_DIM + chk * 8;
        lA[it] = &As[slab * 512];
    }
    const f16* gBd[4]; f16* lBd[4];
#pragma unroll
    for (int it = 0; it < 4; ++it) {
        int slab = it * 4 + w;               // 0..15
        int row = slab * 8 + rsl;            // 0..127
        int brow = ct * 128 + row;
        gBd[it] = wdh + ((size_t)e * H_DIM + brow) * I_DIM + chk * 8;
        lBd[it] = &Bd[slab * 512];
    }

    f32x4 acc[4][4];
#pragma unroll
    for (int i = 0; i < 4; ++i)
#pragma unroll
        for (int j = 0; j < 4; ++j) acc[i][j] = (f32x4)0.f;

    for (int ks = 0; ks < I_DIM / 64; ++ks) {
        const int k0 = ks * 64;
#pragma unroll
        for (int it = 0; it < 4; ++it) async_copy16(gA[it] + k0, lA[it]);
#pragma unroll
        for (int it = 0; it < 4; ++it) async_copy16(gBd[it] + k0, lBd[it]);
        __syncthreads();
#pragma unroll
        for (int kk = 0; kk < 2; ++kk) {
            const int kc = kk * 4;
            const int coff = (((qr + kc) ^ (lc & 7)) << 3);
            f16x8 af[4], bf[4];
#pragma unroll
            for (int mi = 0; mi < 4; ++mi) {
                int r = wm * 64 + mi * 16 + lc;      // 0..127
                af[mi] = *(const f16x8*)&As[r * 64 + coff];
            }
#pragma unroll
            for (int ni = 0; ni < 4; ++ni) {
                int r = wn * 64 + ni * 16 + lc;      // 0..127
                bf[ni] = *(const f16x8*)&Bd[r * 64 + coff];
            }
#pragma unroll
            for (int mi = 0; mi < 4; ++mi)
#pragma unroll
                for (int ni = 0; ni < 4; ++ni)
                    acc[mi][ni] = __builtin_amdgcn_mfma_f32_16x16x32_f16(af[mi], bf[ni], acc[mi][ni], 0, 0, 0);
        }
        __syncthreads();
    }
#pragma unroll
    for (int mi = 0; mi < 4; ++mi)
#pragma unroll
        for (int ni = 0; ni < 4; ++ni)
#pragma unroll
            for (int r = 0; r < 4; ++r) {
                int lrow = rt * 128 + wm * 64 + mi * 16 + qr * 4 + r;
                if (lrow < count) {
                    int col = ct * 128 + wn * 64 + ni * 16 + lc;
                    mid2[(size_t)(offs_e + lrow) * H_DIM + col] = acc[mi][ni][r];
                }
            }
}

// ---------------- combine: out[t] = w0*mid2[slot0] + w1*mid2[slot1] ----------------
__global__ void combine_kernel(const float* __restrict__ mid2, const int* __restrict__ sl,
                               const float* __restrict__ sw, const int* __restrict__ cnt,
                               fvec4* __restrict__ out) {
    const int t = blockIdx.x;
    const int c = threadIdx.x;               // 0..255 float4 per 1024-col row
    int s0 = sl[t * 2], s1 = sl[t * 2 + 1];
    float w0 = sw[t * 2], w1 = sw[t * 2 + 1];
    const int e0 = s0 >> 20, e1 = s1 >> 20;
    int o0 = 0, o1 = 0;                      // inline prefix, predicated (no reg-array idx)
#pragma unroll
    for (int i2 = 0; i2 < NEXP; ++i2) {
        int cc = cnt[i2 * 32];
        o0 += (i2 < e0) ? cc : 0;
        o1 += (i2 < e1) ? cc : 0;
    }
    size_t r0 = (size_t)(o0 + (s0 & 0xFFFFF)) * 256 + c;
    size_t r1 = (size_t)(o1 + (s1 & 0xFFFFF)) * 256 + c;
    const fvec4* m4 = (const fvec4*)mid2;
    fvec4 a = m4[r0], b = m4[r1];
    out[(size_t)t * 256 + c] = w0 * a + w1 * b;
}

extern "C" void kernel_launch(void* const* d_in, const int* in_sizes, int n_in,
                              void* d_out, int out_size, void* d_ws, size_t ws_size,
                              hipStream_t stream) {
    (void)in_sizes; (void)n_in; (void)out_size; (void)ws_size;
    const float* x  = (const float*)d_in[0];
    const float* rw = (const float*)d_in[1];
    const float* wg = (const float*)d_in[2];
    const float* wu = (const float*)d_in[3];
    const float* wd = (const float*)d_in[4];
    float* out = (float*)d_out;

    uint8_t* ws = (uint8_t*)d_ws;
    int*   cnt  = (int*)(ws + 0);              // 8 counters, 128B apart (1024 B)
    int*   tok  = (int*)(ws + 4096);           // 8*8192 ints = 262144 B
    int*   sl   = (int*)(ws + 266240);         // 2*8192 ints = 65536 B
    float* sw   = (float*)(ws + 331776);       // 2*8192 floats = 65536 B
    f16*   xb   = (f16*)(ws + 528384);         // 16,777,216 B
    f16*   mid  = (f16*)(ws + 17305600);       // 16384*2048 f16 = 67,108,864 B
    f16*   wgh  = (f16*)(ws + 84414464);       // 33,554,432 B
    f16*   wuh  = (f16*)(ws + 117968896);      // 33,554,432 B
    f16*   wdh  = (f16*)(ws + 151523328);      // 33,554,432 B  (end 185,077,760)
    // mid2 fp32 [16384][1024] overlays wgh+wuh (dead after gu; rewritten by prep each call)
    float* mid2 = (float*)(ws + 84414464);     // 67,108,864 B

    hipLaunchKernelGGL(init_kernel, dim3(1), dim3(64), 0, stream, cnt);
    hipLaunchKernelGGL(prep_kernel, dim3(CVT_BLOCKS + T_TOK / RBLK), dim3(256), 0, stream,
                       wg, wu, wd, wgh, wuh, wdh, x, rw, cnt, tok, sl, sw, xb);
    // grid: (expert, ct, rt) -> expert pins to an XCD; ct-fast keeps all working
    // blocks dense at the head of dispatch order (empty rt-tail blocks last)
    hipLaunchKernelGGL(gu_kernel, dim3(8, 32, 64), dim3(256), 0, stream, xb, wgh, wuh, cnt, tok, mid);
    hipLaunchKernelGGL(down_kernel, dim3(8, 8, 64), dim3(256), 0, stream, mid, wdh, cnt, mid2);
    hipLaunchKernelGGL(combine_kernel, dim3(8192), dim3(256), 0, stream, mid2, sl, sw, cnt, (fvec4*)out);
}